// Round 14
// baseline (163.903 us; speedup 1.0000x reference)
//
#include <hip/hip_runtime.h>
#include <hip/hip_bf16.h>
#include <hip/hip_fp16.h>

// Problem constants
#define NB 16
#define DD 64
#define HW 4096          // 64*64
#define NTOT 65536       // NB*HW
#define KC 1024

// Output chunk offsets (FLOAT32 elements, return order)
#define O_EK   0
#define O_IDX  4194304
#define O_L    4259840
#define O_CB   4259841
#define O_CNT  4325377
#define O_SUM  4326401

// Workspace layout (float element offsets)
#define WS_IDX    0          // [0, 65536) int32
#define WS_LCPART 65536      // 256 floats used
#define WS_N      66048      // scalar
#define WS_CNORM  66560      // 1024
#define WS_PSUM   67584      // 4 x 65536 -> ends 329728
#define WS_PCNT   329728     // 4 x 1024 ints -> ends 333824
#define WS_FLGC   333824     // 512 ints
#define WS_FLGL   334336     // 512 x 32 ints -> ends 350720
#define WS_CBH    399360     // 65536 ushort
#define WS_CBL    432128     // 65536 ushort

#define MARGIN 0.002f
#define MAXFLG 32

typedef _Float16 v8h __attribute__((ext_vector_type(8)));
typedef float    v4f __attribute__((ext_vector_type(4)));

// cnorm + n + codebook fp16 hi/lo split
__global__ __launch_bounds__(256) void k_pre(const float* __restrict__ cb,
                                             const float* __restrict__ ema_count,
                                             float* __restrict__ cnorm,
                                             float* __restrict__ n_ws,
                                             unsigned short* __restrict__ cbh,
                                             unsigned short* __restrict__ cbl) {
    const int t = threadIdx.x;
    const int w = (blockIdx.x * 256 + t) >> 6;   // code 0..1023 (grid 256)
    const int l = t & 63;
    float s = 0.f;
    if (l < 16) {
        float4 v = *(const float4*)(cb + (size_t)w * DD + l * 4);
        s = v.x * v.x + v.y * v.y + v.z * v.z + v.w * v.w;
    }
#pragma unroll
    for (int m = 1; m <= 8; m <<= 1) s += __shfl_xor(s, m, 64);
    if (l == 0) cnorm[w] = s;

    // fp16 hi/lo conversion: 16384 float4s
    const int e4 = blockIdx.x * 256 + t;
    if (e4 < 16384) {
        float4 v4 = ((const float4*)cb)[e4];
        __half hx = __float2half(v4.x), hy = __float2half(v4.y),
               hz = __float2half(v4.z), hw2 = __float2half(v4.w);
        ushort4 h4 = { __half_as_ushort(hx), __half_as_ushort(hy),
                       __half_as_ushort(hz), __half_as_ushort(hw2) };
        ((ushort4*)cbh)[e4] = h4;
        ushort4 l4 = { __half_as_ushort(__float2half(v4.x - __half2float(hx))),
                       __half_as_ushort(__float2half(v4.y - __half2float(hy))),
                       __half_as_ushort(__float2half(v4.z - __half2float(hz))),
                       __half_as_ushort(__float2half(v4.w - __half2float(hw2))) };
        ((ushort4*)cbl)[e4] = l4;
    }

    if (blockIdx.x == 0) {
        __shared__ float red[256];
        red[t] = ema_count[t] + ema_count[t + 256] + ema_count[t + 512] + ema_count[t + 768];
        __syncthreads();
        for (int s2 = 128; s2 >= 1; s2 >>= 1) {
            if (t < s2) red[t] += red[t + s2];
            __syncthreads();
        }
        if (t == 0) n_ws[0] = 0.99f * red[0] + 0.01f * 65536.0f;
    }
}

// MFMA argmin, 50.6 KB LDS -> 3 blocks/CU. Chunked fragment-native layouts.
// Block 256 = 4 waves; wave = 32 rows; 512 blocks; 16 B-tiles of 64 codes.
__global__ __launch_bounds__(256) void k_argmin(const float* __restrict__ z_e,
                                                const unsigned short* __restrict__ cbh,
                                                const unsigned short* __restrict__ cbl,
                                                const float* __restrict__ cnorm,
                                                int* __restrict__ idx_ws,
                                                int* __restrict__ flg_cnt,
                                                int* __restrict__ flg_list,
                                                float* __restrict__ out) {
    // chunk ch = j/8; element [ch][row][j%8] — one v8h fragment slice per row-chunk
    __shared__ __align__(16) unsigned short A2h[8][128][8];  // 16 KB
    __shared__ __align__(16) unsigned short A2l[8][128][8];  // 16 KB
    __shared__ __align__(16) unsigned short B2h[8][64][8];   // 8 KB (aliased: fp32 A slab)
    __shared__ __align__(16) unsigned short B2l[8][64][8];   // 8 KB
    __shared__ int idx_lds[128];
    __shared__ int flagrows[128];
    __shared__ int nflag;

    float* slab = (float*)&B2h[0][0][0];   // 2048 floats = 16 j x 128 m

    const int t  = threadIdx.x;
    const int n0 = blockIdx.x * 128;
    const int b   = n0 >> 12;
    const int hw0 = n0 & 4095;
    const float* zbase = z_e + (size_t)b * (DD * HW) + hw0;

    if (t == 0) nflag = 0;

    // ---- A staging: 4 slabs of 16 j-rows; coalesced fp32 load, then hi/lo convert ----
    for (int sl = 0; sl < 4; ++sl) {
        __syncthreads();                    // protect slab region from previous readers
#pragma unroll
        for (int s = 0; s < 2; ++s) {
            int idx = t + s * 256;          // 0..511 float4s
            int j   = idx >> 5;             // 0..15
            int m4  = (idx & 31) << 2;
            float4 v = *(const float4*)(zbase + (size_t)(sl * 16 + j) * HW + m4);
            *(float4*)&slab[j * 128 + m4] = v;
        }
        __syncthreads();
        {
            const int chl = t >> 7;         // 0..1 (local chunk)
            const int m   = t & 127;
            const int ch  = sl * 2 + chl;
            unsigned hv[4], lv[4];
#pragma unroll
            for (int p = 0; p < 4; ++p) {
                float v0 = slab[(chl * 8 + 2 * p    ) * 128 + m];
                float v1 = slab[(chl * 8 + 2 * p + 1) * 128 + m];
                __half h0 = __float2half(v0), h1 = __float2half(v1);
                __half l0 = __float2half(v0 - __half2float(h0));
                __half l1 = __float2half(v1 - __half2float(h1));
                hv[p] = (unsigned)__half_as_ushort(h0) | ((unsigned)__half_as_ushort(h1) << 16);
                lv[p] = (unsigned)__half_as_ushort(l0) | ((unsigned)__half_as_ushort(l1) << 16);
            }
            uint4 hq = {hv[0], hv[1], hv[2], hv[3]};
            uint4 lq = {lv[0], lv[1], lv[2], lv[3]};
            *(uint4*)&A2h[ch][m][0] = hq;
            *(uint4*)&A2l[ch][m][0] = lq;
        }
    }
    __syncthreads();

    const int w    = t >> 6;        // wave 0..3 -> rows [32w, 32w+32)
    const int lane = t & 63;
    const int c    = lane & 15;     // col within 16-tile
    const int q    = lane >> 4;     // k-quad / row-quad

    // A fragments, loaded once: [group g][K-step s]; chunk = s*4 + q
    v8h Afh[2][2], Afl[2][2];
#pragma unroll
    for (int g = 0; g < 2; ++g) {
        int m = 32 * w + 16 * g + c;
#pragma unroll
        for (int s = 0; s < 2; ++s) {
            Afh[g][s] = *(const v8h*)&A2h[s * 4 + q][m][0];
            Afl[g][s] = *(const v8h*)&A2l[s * 4 + q][m][0];
        }
    }

    float m1v[2][4], m2v[2][4]; int m1i[2][4];
#pragma unroll
    for (int g = 0; g < 2; ++g)
#pragma unroll
        for (int r = 0; r < 4; ++r) { m1v[g][r] = 3.4e38f; m2v[g][r] = 3.4e38f; m1i[g][r] = 0; }

    for (int kt = 0; kt < 16; ++kt) {
        __syncthreads();
        // stage 64 codes (hi+lo): 512 uint4 per array, 2 each per thread
#pragma unroll
        for (int s2 = 0; s2 < 2; ++s2) {
            int idx  = t + s2 * 256;        // 0..511
            int ch   = idx >> 6;            // 0..7
            int code = idx & 63;
            size_t gsrc = ((size_t)(kt * 64 + code)) * 64 + ch * 8;
            *(uint4*)&B2h[ch][code][0] = *(const uint4*)(cbh + gsrc);
            *(uint4*)&B2l[ch][code][0] = *(const uint4*)(cbl + gsrc);
        }
        __syncthreads();

#pragma unroll
        for (int sub = 0; sub < 4; ++sub) {
            const int cl = sub * 16 + c;
            v8h Bfh0 = *(const v8h*)&B2h[q][cl][0];
            v8h Bfh1 = *(const v8h*)&B2h[4 + q][cl][0];
            v8h Bfl0 = *(const v8h*)&B2l[q][cl][0];
            v8h Bfl1 = *(const v8h*)&B2l[4 + q][cl][0];
            const int kg = kt * 64 + cl;
            float cnc = cnorm[kg];          // 4 KB array, L1-hot
#pragma unroll
            for (int g = 0; g < 2; ++g) {
                v4f acc = {0.f, 0.f, 0.f, 0.f};
                acc = __builtin_amdgcn_mfma_f32_16x16x32_f16(Afh[g][0], Bfh0, acc, 0, 0, 0);
                acc = __builtin_amdgcn_mfma_f32_16x16x32_f16(Afh[g][1], Bfh1, acc, 0, 0, 0);
                acc = __builtin_amdgcn_mfma_f32_16x16x32_f16(Afh[g][0], Bfl0, acc, 0, 0, 0);
                acc = __builtin_amdgcn_mfma_f32_16x16x32_f16(Afh[g][1], Bfl1, acc, 0, 0, 0);
                acc = __builtin_amdgcn_mfma_f32_16x16x32_f16(Afl[g][0], Bfh0, acc, 0, 0, 0);
                acc = __builtin_amdgcn_mfma_f32_16x16x32_f16(Afl[g][1], Bfh1, acc, 0, 0, 0);
#pragma unroll
                for (int r = 0; r < 4; ++r) {
                    float v = fmaf(-2.0f, acc[r], cnc);   // zn omitted: per-row constant
                    bool better = v < m1v[g][r];          // strict: kg ascending keeps first
                    m2v[g][r] = better ? m1v[g][r] : fminf(m2v[g][r], v);
                    m1i[g][r] = better ? kg : m1i[g][r];
                    m1v[g][r] = better ? v : m1v[g][r];
                }
            }
        }
    }

    // ---- top-2 merge across the 16 lanes holding each row ----
#pragma unroll
    for (int g = 0; g < 2; ++g)
#pragma unroll
        for (int r = 0; r < 4; ++r) {
            float a = m1v[g][r], b2 = m2v[g][r]; int ii = m1i[g][r];
#pragma unroll
            for (int mask = 1; mask <= 8; mask <<= 1) {
                float ov = __shfl_xor(a, mask, 64);
                int   oi = __shfl_xor(ii, mask, 64);
                float o2 = __shfl_xor(b2, mask, 64);
                bool take = (ov < a) || (ov == a && oi < ii);
                float loser = take ? a : ov;
                b2 = fminf(fminf(b2, o2), loser);
                a  = take ? ov : a;
                ii = take ? oi : ii;
            }
            if (c == 0) {
                int row = 32 * w + 16 * g + q * 4 + r;
                idx_lds[row] = ii;
                if ((b2 - a) < MARGIN) { int p = atomicAdd(&nflag, 1); flagrows[p] = row; }
            }
        }
    __syncthreads();

    // export flags for k_fix (per-block slots, no contention)
    int nf = nflag; if (nf > MAXFLG) nf = MAXFLG;
    if (t == 0) flg_cnt[blockIdx.x] = nf;
    if (t < nf) flg_list[blockIdx.x * MAXFLG + t] = flagrows[t];

    if (t < 128) {
        int bi = idx_lds[t];
        out[O_IDX + n0 + t] = (float)bi;      // provisional for flagged rows; k_fix overwrites
        idx_ws[n0 + t] = bi;
    }
}

// Exact fp32 re-argmin for flagged rows only. Grid = 512 (one per argmin block).
__global__ __launch_bounds__(256) void k_fix(const float* __restrict__ z_e,
                                             const float* __restrict__ cb,
                                             const float* __restrict__ cnorm,
                                             const int* __restrict__ flg_cnt,
                                             const int* __restrict__ flg_list,
                                             int* __restrict__ idx_ws,
                                             float* __restrict__ out) {
    const int blk = blockIdx.x;
    const int nf = flg_cnt[blk];
    if (nf == 0) return;
    __shared__ float redv4[4];
    __shared__ int   redi4[4];
    const int t = threadIdx.x;
    const int lane = t & 63, w = t >> 6;
    const int n0 = blk * 128;
    const int b   = n0 >> 12;
    const int hw0 = n0 & 4095;

    for (int f = 0; f < nf; ++f) {
        int row = flg_list[blk * MAXFLG + f];
        const float* zrow = z_e + (size_t)b * (DD * HW) + hw0 + row;
        float znr = 0.f;
        for (int j = 0; j < 64; ++j) { float v = zrow[(size_t)j * HW]; znr = fmaf(v, v, znr); }
        float best = 3.4e38f; int bi = 0;
#pragma unroll
        for (int c2 = 0; c2 < 4; ++c2) {
            int k = t * 4 + c2;                      // ascending within thread
            const float* ck = cb + (size_t)k * DD;
            float acc = 0.f;
            for (int j = 0; j < 64; ++j) acc = fmaf(zrow[(size_t)j * HW], ck[j], acc);
            float v = (znr - 2.0f * acc) + cnorm[k];
            if (v < best) { best = v; bi = k; }
        }
#pragma unroll
        for (int mask = 1; mask <= 32; mask <<= 1) {
            float ov = __shfl_xor(best, mask, 64);
            int   oi = __shfl_xor(bi, mask, 64);
            if (ov < best || (ov == best && oi < bi)) { best = ov; bi = oi; }
        }
        if (lane == 0) { redv4[w] = best; redi4[w] = bi; }
        __syncthreads();
        if (t == 0) {
            float bv = redv4[0]; int bix = redi4[0];
#pragma unroll
            for (int w2 = 1; w2 < 4; ++w2)
                if (redv4[w2] < bv || (redv4[w2] == bv && redi4[w2] < bix)) { bv = redv4[w2]; bix = redi4[w2]; }
            idx_ws[n0 + row] = bix;
            out[O_IDX + n0 + row] = (float)bix;
        }
        __syncthreads();
    }
}

// Fused output pass: 256 blocks (j, chunk c). Reads z once: e_k_ste + segment sums
// + histogram (j==0) + L_commit partials. cb column j staged in LDS.
__global__ __launch_bounds__(1024) void k_out(const int* __restrict__ idx_ws,
                                              const float* __restrict__ z_e,
                                              const float* __restrict__ cb,
                                              float* __restrict__ psum,
                                              int* __restrict__ pcnt,
                                              float* __restrict__ lc_part,
                                              float* __restrict__ out) {
    __shared__ float acc[KC];
    __shared__ int bins[KC];
    __shared__ float cbj[KC];
    __shared__ float lcr[16];
    const int j = blockIdx.x & 63;
    const int c = blockIdx.x >> 6;
    const int t = threadIdx.x;
    acc[t] = 0.f;
    bins[t] = 0;
    cbj[t] = cb[(size_t)t * DD + j];   // codebook column j (once per block)
    __syncthreads();
    const float* zj = z_e + (size_t)j * HW;
    float* oj = out + O_EK + (size_t)j * HW;
    const int base = c * 16384;
    float lc = 0.f;
#pragma unroll
    for (int i = 0; i < 4; ++i) {
        int n4 = base + i * 4096 + t * 4;
        int b = n4 >> 12, hw = n4 & 4095;
        size_t zoff = (size_t)b * (DD * HW) + hw;
        float4 z4 = *(const float4*)(zj + zoff);
        int4   k4 = *(const int4*)(idx_ws + n4);
        float e0 = cbj[k4.x], e1 = cbj[k4.y], e2 = cbj[k4.z], e3 = cbj[k4.w];
        float4 o4 = { z4.x + (e0 - z4.x), z4.y + (e1 - z4.y),
                      z4.z + (e2 - z4.z), z4.w + (e3 - z4.w) };
        *(float4*)(oj + zoff) = o4;                       // coalesced
        float d0 = z4.x - e0, d1 = z4.y - e1, d2 = z4.z - e2, d3 = z4.w - e3;
        lc = fmaf(d0, d0, lc); lc = fmaf(d1, d1, lc);
        lc = fmaf(d2, d2, lc); lc = fmaf(d3, d3, lc);
        atomicAdd(&acc[k4.x], z4.x);
        atomicAdd(&acc[k4.y], z4.y);
        atomicAdd(&acc[k4.z], z4.z);
        atomicAdd(&acc[k4.w], z4.w);
        if (j == 0) {
            atomicAdd(&bins[k4.x], 1); atomicAdd(&bins[k4.y], 1);
            atomicAdd(&bins[k4.z], 1); atomicAdd(&bins[k4.w], 1);
        }
    }
    __syncthreads();
    psum[(size_t)c * 65536 + j * 1024 + t] = acc[t];
    if (j == 0) pcnt[c * 1024 + t] = bins[t];
#pragma unroll
    for (int m = 32; m >= 1; m >>= 1) lc += __shfl_xor(lc, m, 64);
    if ((t & 63) == 0) lcr[t >> 6] = lc;
    __syncthreads();
    if (t == 0) {
        float s = 0.f;
#pragma unroll
        for (int u = 0; u < 16; ++u) s += lcr[u];
        lc_part[blockIdx.x] = s;
    }
}

// Fused epilogue, coalesced on outputs: e = k*64+j. 64 blocks x 1024.
__global__ __launch_bounds__(1024) void k_epi(const float* __restrict__ psum,
                                              const int* __restrict__ pcnt,
                                              const float* __restrict__ ema_sum,
                                              const float* __restrict__ ema_count,
                                              const float* __restrict__ n_ws,
                                              const float* __restrict__ lc_part,
                                              float* __restrict__ out) {
    const int t = threadIdx.x;
    const int e = blockIdx.x * 1024 + t;
    const int k = e >> 6, j = e & 63;
    float s4 = psum[j * 1024 + k] + psum[65536 + j * 1024 + k]
             + psum[131072 + j * 1024 + k] + psum[196608 + j * 1024 + k];
    float ns = ema_sum[e] * 0.99f + 0.01f * s4;
    out[O_SUM + e] = ns;
    int cnt = pcnt[k] + pcnt[1024 + k] + pcnt[2048 + k] + pcnt[3072 + k];
    float nc = ema_count[k] * 0.99f + 0.01f * (float)cnt;
    float n  = n_ws[0];
    float cs = (nc + 1e-5f) / (n + 1024.0f * 1e-5f) * n;
    out[O_CB + e] = ns / cs;
    if (blockIdx.x == 0) {
        int c2 = pcnt[t] + pcnt[1024 + t] + pcnt[2048 + t] + pcnt[3072 + t];
        out[O_CNT + t] = ema_count[t] * 0.99f + 0.01f * (float)c2;
    }
    if (blockIdx.x == 1) {
        __shared__ float red[512];
        if (t < 512) red[t] = (t < 256) ? lc_part[t] : 0.f;
        __syncthreads();
        for (int s = 256; s >= 1; s >>= 1) {
            if (t < s) red[t] += red[t + s];
            __syncthreads();
        }
        if (t == 0) out[O_L] = 1.25f * red[0] * (1.0f / 4194304.0f);
    }
}

extern "C" void kernel_launch(void* const* d_in, const int* in_sizes, int n_in,
                              void* d_out, int out_size, void* d_ws, size_t ws_size,
                              hipStream_t stream) {
    const float* z_e       = (const float*)d_in[0];
    const float* cb        = (const float*)d_in[1];
    const float* ema_count = (const float*)d_in[2];
    const float* ema_sum   = (const float*)d_in[3];
    float* out             = (float*)d_out;

    float* ws_f      = (float*)d_ws;
    int*   idx_ws    = (int*)d_ws;
    float* lc_part   = ws_f + WS_LCPART;
    float* n_ws      = ws_f + WS_N;
    float* cnorm_ws  = ws_f + WS_CNORM;
    float* psum      = ws_f + WS_PSUM;
    int*   pcnt      = (int*)(ws_f + WS_PCNT);
    int*   flg_cnt   = (int*)(ws_f + WS_FLGC);
    int*   flg_list  = (int*)(ws_f + WS_FLGL);
    unsigned short* cbh = (unsigned short*)(ws_f + WS_CBH);
    unsigned short* cbl = (unsigned short*)(ws_f + WS_CBL);

    k_pre<<<256, 256, 0, stream>>>(cb, ema_count, cnorm_ws, n_ws, cbh, cbl);
    k_argmin<<<NTOT / 128, 256, 0, stream>>>(z_e, cbh, cbl, cnorm_ws, idx_ws, flg_cnt, flg_list, out);
    k_fix<<<NTOT / 128, 256, 0, stream>>>(z_e, cb, cnorm_ws, flg_cnt, flg_list, idx_ws, out);
    k_out<<<256, 1024, 0, stream>>>(idx_ws, z_e, cb, psum, pcnt, lc_part, out);
    k_epi<<<64, 1024, 0, stream>>>(psum, pcnt, ema_sum, ema_count, n_ws, lc_part, out);
}

// Round 15
// 158.917 us; speedup vs baseline: 1.0314x; 1.0314x over previous
//
#include <hip/hip_runtime.h>
#include <hip/hip_bf16.h>
#include <hip/hip_fp16.h>

// Problem constants
#define NB 16
#define DD 64
#define HW 4096          // 64*64
#define NTOT 65536       // NB*HW
#define KC 1024

// Output chunk offsets (FLOAT32 elements, return order)
#define O_EK   0
#define O_IDX  4194304
#define O_L    4259840
#define O_CB   4259841
#define O_CNT  4325377
#define O_SUM  4326401

// Workspace layout (float element offsets)
#define WS_IDX    0          // [0, 65536) int32
#define WS_LCPART 65536      // 256 floats used
#define WS_N      66048      // scalar
#define WS_CNORM  66560      // 1024
#define WS_PSUM   67584      // 4 x 65536 -> ends 329728
#define WS_PCNT   329728     // 4 x 1024 ints -> ends 333824
#define WS_FLGC   333824     // 512 ints
#define WS_FLGL   334336     // 512 x 32 ints -> ends 350720
#define WS_CBH    399360     // 65536 ushort
#define WS_CBL    432128     // 65536 ushort

#define MARGIN 0.002f
#define MAXFLG 32

typedef _Float16 v8h __attribute__((ext_vector_type(8)));
typedef float    v4f __attribute__((ext_vector_type(4)));

// cnorm + n + codebook fp16 hi/lo split
__global__ __launch_bounds__(256) void k_pre(const float* __restrict__ cb,
                                             const float* __restrict__ ema_count,
                                             float* __restrict__ cnorm,
                                             float* __restrict__ n_ws,
                                             unsigned short* __restrict__ cbh,
                                             unsigned short* __restrict__ cbl) {
    const int t = threadIdx.x;
    const int w = (blockIdx.x * 256 + t) >> 6;   // code 0..1023 (grid 256)
    const int l = t & 63;
    float s = 0.f;
    if (l < 16) {
        float4 v = *(const float4*)(cb + (size_t)w * DD + l * 4);
        s = v.x * v.x + v.y * v.y + v.z * v.z + v.w * v.w;
    }
#pragma unroll
    for (int m = 1; m <= 8; m <<= 1) s += __shfl_xor(s, m, 64);
    if (l == 0) cnorm[w] = s;

    // fp16 hi/lo conversion: 16384 float4s
    const int e4 = blockIdx.x * 256 + t;
    if (e4 < 16384) {
        float4 v4 = ((const float4*)cb)[e4];
        __half hx = __float2half(v4.x), hy = __float2half(v4.y),
               hz = __float2half(v4.z), hw2 = __float2half(v4.w);
        ushort4 h4 = { __half_as_ushort(hx), __half_as_ushort(hy),
                       __half_as_ushort(hz), __half_as_ushort(hw2) };
        ((ushort4*)cbh)[e4] = h4;
        ushort4 l4 = { __half_as_ushort(__float2half(v4.x - __half2float(hx))),
                       __half_as_ushort(__float2half(v4.y - __half2float(hy))),
                       __half_as_ushort(__float2half(v4.z - __half2float(hz))),
                       __half_as_ushort(__float2half(v4.w - __half2float(hw2))) };
        ((ushort4*)cbl)[e4] = l4;
    }

    if (blockIdx.x == 0) {
        __shared__ float red[256];
        red[t] = ema_count[t] + ema_count[t + 256] + ema_count[t + 512] + ema_count[t + 768];
        __syncthreads();
        for (int s2 = 128; s2 >= 1; s2 >>= 1) {
            if (t < s2) red[t] += red[t + s2];
            __syncthreads();
        }
        if (t == 0) n_ws[0] = 0.99f * red[0] + 0.01f * 65536.0f;
    }
}

// MFMA argmin, double-buffered B staging: ONE barrier per K-iteration.
// Block 256 = 4 waves; wave = 32 rows; 512 blocks; 16 B-tiles of 64 codes.
__global__ __launch_bounds__(256) void k_argmin(const float* __restrict__ z_e,
                                                const unsigned short* __restrict__ cbh,
                                                const unsigned short* __restrict__ cbl,
                                                const float* __restrict__ cnorm,
                                                int* __restrict__ idx_ws,
                                                int* __restrict__ flg_cnt,
                                                int* __restrict__ flg_list,
                                                float* __restrict__ out) {
    // chunk ch = j/8; element [ch][row][j%8] — one v8h fragment slice per row-chunk
    __shared__ __align__(16) unsigned short A2h[8][128][8];    // 16 KB
    __shared__ __align__(16) unsigned short A2l[8][128][8];    // 16 KB
    __shared__ __align__(16) unsigned short B2h[2][8][64][8];  // 16 KB (buf0 aliased: fp32 A slab)
    __shared__ __align__(16) unsigned short B2l[2][8][64][8];  // 16 KB
    __shared__ int idx_lds[128];
    __shared__ int flagrows[128];
    __shared__ int nflag;

    float* slab = (float*)&B2h[0][0][0][0];   // 4096 floats = 32 j x 128 m

    const int t  = threadIdx.x;
    const int n0 = blockIdx.x * 128;
    const int b   = n0 >> 12;
    const int hw0 = n0 & 4095;
    const float* zbase = z_e + (size_t)b * (DD * HW) + hw0;

    if (t == 0) nflag = 0;

    // ---- A staging: 2 slabs of 32 j-rows; coalesced fp32 load, then hi/lo convert ----
    for (int sl = 0; sl < 2; ++sl) {
        if (sl) __syncthreads();            // protect slab from previous convert-readers
#pragma unroll
        for (int s = 0; s < 4; ++s) {
            int idx = t + s * 256;          // 0..1023 float4s
            int j   = idx >> 5;             // 0..31
            int m4  = (idx & 31) << 2;
            float4 v = *(const float4*)(zbase + (size_t)(sl * 32 + j) * HW + m4);
            *(float4*)&slab[j * 128 + m4] = v;
        }
        __syncthreads();
#pragma unroll
        for (int s = 0; s < 2; ++s) {
            int ss  = t + s * 256;          // 0..511 fragment slices
            int chl = ss >> 7;              // 0..3 local chunk
            int m   = ss & 127;
            int ch  = sl * 4 + chl;
            unsigned hv[4], lv[4];
#pragma unroll
            for (int p = 0; p < 4; ++p) {
                float v0 = slab[(chl * 8 + 2 * p    ) * 128 + m];
                float v1 = slab[(chl * 8 + 2 * p + 1) * 128 + m];
                __half h0 = __float2half(v0), h1 = __float2half(v1);
                __half l0 = __float2half(v0 - __half2float(h0));
                __half l1 = __float2half(v1 - __half2float(h1));
                hv[p] = (unsigned)__half_as_ushort(h0) | ((unsigned)__half_as_ushort(h1) << 16);
                lv[p] = (unsigned)__half_as_ushort(l0) | ((unsigned)__half_as_ushort(l1) << 16);
            }
            uint4 hq = {hv[0], hv[1], hv[2], hv[3]};
            uint4 lq = {lv[0], lv[1], lv[2], lv[3]};
            *(uint4*)&A2h[ch][m][0] = hq;
            *(uint4*)&A2l[ch][m][0] = lq;
        }
    }
    __syncthreads();                        // A2 complete; slab (B buf0) dead

    const int w    = t >> 6;        // wave 0..3 -> rows [32w, 32w+32)
    const int lane = t & 63;
    const int c    = lane & 15;     // col within 16-tile
    const int q    = lane >> 4;     // k-quad / row-quad

    // staging decomposition (used for prologue + prefetch)
    const int ch0   = t >> 6;               // idx = t      -> ch 0..3
    const int code0 = t & 63;
    const int ch1   = 4 + (t >> 6);         // idx = t+256  -> ch 4..7
    const int code1 = t & 63;

    // A fragments, loaded once: [group g][K-step s]; chunk = s*4 + q
    v8h Afh[2][2], Afl[2][2];
#pragma unroll
    for (int g = 0; g < 2; ++g) {
        int m = 32 * w + 16 * g + c;
#pragma unroll
        for (int s = 0; s < 2; ++s) {
            Afh[g][s] = *(const v8h*)&A2h[s * 4 + q][m][0];
            Afl[g][s] = *(const v8h*)&A2l[s * 4 + q][m][0];
        }
    }

    // ---- prologue: stage B tile 0 into buffer 0 ----
    {
        size_t g0 = ((size_t)code0) * 64 + ch0 * 8;
        size_t g1 = ((size_t)code1) * 64 + ch1 * 8;
        *(uint4*)&B2h[0][ch0][code0][0] = *(const uint4*)(cbh + g0);
        *(uint4*)&B2l[0][ch0][code0][0] = *(const uint4*)(cbl + g0);
        *(uint4*)&B2h[0][ch1][code1][0] = *(const uint4*)(cbh + g1);
        *(uint4*)&B2l[0][ch1][code1][0] = *(const uint4*)(cbl + g1);
    }
    __syncthreads();

    float m1v[2][4], m2v[2][4]; int m1i[2][4];
#pragma unroll
    for (int g = 0; g < 2; ++g)
#pragma unroll
        for (int r = 0; r < 4; ++r) { m1v[g][r] = 3.4e38f; m2v[g][r] = 3.4e38f; m1i[g][r] = 0; }

    for (int kt = 0; kt < 16; ++kt) {
        const int cur = kt & 1, nxt = cur ^ 1;
        // prefetch tile kt+1 into VGPRs (loads overlap compute below)
        uint4 ph0, pl0, ph1, pl1;
        if (kt < 15) {
            size_t g0 = ((size_t)((kt + 1) * 64 + code0)) * 64 + ch0 * 8;
            size_t g1 = ((size_t)((kt + 1) * 64 + code1)) * 64 + ch1 * 8;
            ph0 = *(const uint4*)(cbh + g0);
            pl0 = *(const uint4*)(cbl + g0);
            ph1 = *(const uint4*)(cbh + g1);
            pl1 = *(const uint4*)(cbl + g1);
        }

        // compute tile kt from buf[cur]
#pragma unroll
        for (int sub = 0; sub < 4; ++sub) {
            const int cl = sub * 16 + c;
            v8h Bfh0 = *(const v8h*)&B2h[cur][q][cl][0];
            v8h Bfh1 = *(const v8h*)&B2h[cur][4 + q][cl][0];
            v8h Bfl0 = *(const v8h*)&B2l[cur][q][cl][0];
            v8h Bfl1 = *(const v8h*)&B2l[cur][4 + q][cl][0];
            const int kg = kt * 64 + cl;
            float cnc = cnorm[kg];          // 4 KB array, L1-hot
#pragma unroll
            for (int g = 0; g < 2; ++g) {
                v4f acc = {0.f, 0.f, 0.f, 0.f};
                acc = __builtin_amdgcn_mfma_f32_16x16x32_f16(Afh[g][0], Bfh0, acc, 0, 0, 0);
                acc = __builtin_amdgcn_mfma_f32_16x16x32_f16(Afh[g][1], Bfh1, acc, 0, 0, 0);
                acc = __builtin_amdgcn_mfma_f32_16x16x32_f16(Afh[g][0], Bfl0, acc, 0, 0, 0);
                acc = __builtin_amdgcn_mfma_f32_16x16x32_f16(Afh[g][1], Bfl1, acc, 0, 0, 0);
                acc = __builtin_amdgcn_mfma_f32_16x16x32_f16(Afl[g][0], Bfh0, acc, 0, 0, 0);
                acc = __builtin_amdgcn_mfma_f32_16x16x32_f16(Afl[g][1], Bfh1, acc, 0, 0, 0);
#pragma unroll
                for (int r = 0; r < 4; ++r) {
                    float v = fmaf(-2.0f, acc[r], cnc);   // zn omitted: per-row constant
                    bool better = v < m1v[g][r];          // strict: kg ascending keeps first
                    m2v[g][r] = better ? m1v[g][r] : fminf(m2v[g][r], v);
                    m1i[g][r] = better ? kg : m1i[g][r];
                    m1v[g][r] = better ? v : m1v[g][r];
                }
            }
        }

        // write prefetched tile into buf[nxt] (its readers passed the last barrier)
        if (kt < 15) {
            *(uint4*)&B2h[nxt][ch0][code0][0] = ph0;
            *(uint4*)&B2l[nxt][ch0][code0][0] = pl0;
            *(uint4*)&B2h[nxt][ch1][code1][0] = ph1;
            *(uint4*)&B2l[nxt][ch1][code1][0] = pl1;
        }
        __syncthreads();                    // single barrier per iteration
    }

    // ---- top-2 merge across the 16 lanes holding each row ----
#pragma unroll
    for (int g = 0; g < 2; ++g)
#pragma unroll
        for (int r = 0; r < 4; ++r) {
            float a = m1v[g][r], b2 = m2v[g][r]; int ii = m1i[g][r];
#pragma unroll
            for (int mask = 1; mask <= 8; mask <<= 1) {
                float ov = __shfl_xor(a, mask, 64);
                int   oi = __shfl_xor(ii, mask, 64);
                float o2 = __shfl_xor(b2, mask, 64);
                bool take = (ov < a) || (ov == a && oi < ii);
                float loser = take ? a : ov;
                b2 = fminf(fminf(b2, o2), loser);
                a  = take ? ov : a;
                ii = take ? oi : ii;
            }
            if (c == 0) {
                int row = 32 * w + 16 * g + q * 4 + r;
                idx_lds[row] = ii;
                if ((b2 - a) < MARGIN) { int p = atomicAdd(&nflag, 1); flagrows[p] = row; }
            }
        }
    __syncthreads();

    // export flags for k_fix (per-block slots, no contention)
    int nf = nflag; if (nf > MAXFLG) nf = MAXFLG;
    if (t == 0) flg_cnt[blockIdx.x] = nf;
    if (t < nf) flg_list[blockIdx.x * MAXFLG + t] = flagrows[t];

    if (t < 128) {
        int bi = idx_lds[t];
        out[O_IDX + n0 + t] = (float)bi;      // provisional for flagged rows; k_fix overwrites
        idx_ws[n0 + t] = bi;
    }
}

// Exact fp32 re-argmin for flagged rows only. Grid = 512 (one per argmin block).
__global__ __launch_bounds__(256) void k_fix(const float* __restrict__ z_e,
                                             const float* __restrict__ cb,
                                             const float* __restrict__ cnorm,
                                             const int* __restrict__ flg_cnt,
                                             const int* __restrict__ flg_list,
                                             int* __restrict__ idx_ws,
                                             float* __restrict__ out) {
    const int blk = blockIdx.x;
    const int nf = flg_cnt[blk];
    if (nf == 0) return;
    __shared__ float redv4[4];
    __shared__ int   redi4[4];
    const int t = threadIdx.x;
    const int lane = t & 63, w = t >> 6;
    const int n0 = blk * 128;
    const int b   = n0 >> 12;
    const int hw0 = n0 & 4095;

    for (int f = 0; f < nf; ++f) {
        int row = flg_list[blk * MAXFLG + f];
        const float* zrow = z_e + (size_t)b * (DD * HW) + hw0 + row;
        float znr = 0.f;
        for (int j = 0; j < 64; ++j) { float v = zrow[(size_t)j * HW]; znr = fmaf(v, v, znr); }
        float best = 3.4e38f; int bi = 0;
#pragma unroll
        for (int c2 = 0; c2 < 4; ++c2) {
            int k = t * 4 + c2;                      // ascending within thread
            const float* ck = cb + (size_t)k * DD;
            float acc = 0.f;
            for (int j = 0; j < 64; ++j) acc = fmaf(zrow[(size_t)j * HW], ck[j], acc);
            float v = (znr - 2.0f * acc) + cnorm[k];
            if (v < best) { best = v; bi = k; }
        }
#pragma unroll
        for (int mask = 1; mask <= 32; mask <<= 1) {
            float ov = __shfl_xor(best, mask, 64);
            int   oi = __shfl_xor(bi, mask, 64);
            if (ov < best || (ov == best && oi < bi)) { best = ov; bi = oi; }
        }
        if (lane == 0) { redv4[w] = best; redi4[w] = bi; }
        __syncthreads();
        if (t == 0) {
            float bv = redv4[0]; int bix = redi4[0];
#pragma unroll
            for (int w2 = 1; w2 < 4; ++w2)
                if (redv4[w2] < bv || (redv4[w2] == bv && redi4[w2] < bix)) { bv = redv4[w2]; bix = redi4[w2]; }
            idx_ws[n0 + row] = bix;
            out[O_IDX + n0 + row] = (float)bix;
        }
        __syncthreads();
    }
}

// Fused output pass: 256 blocks (j, chunk c). Reads z once: e_k_ste + segment sums
// + histogram (j==0) + L_commit partials. cb column j staged in LDS.
__global__ __launch_bounds__(1024) void k_out(const int* __restrict__ idx_ws,
                                              const float* __restrict__ z_e,
                                              const float* __restrict__ cb,
                                              float* __restrict__ psum,
                                              int* __restrict__ pcnt,
                                              float* __restrict__ lc_part,
                                              float* __restrict__ out) {
    __shared__ float acc[KC];
    __shared__ int bins[KC];
    __shared__ float cbj[KC];
    __shared__ float lcr[16];
    const int j = blockIdx.x & 63;
    const int c = blockIdx.x >> 6;
    const int t = threadIdx.x;
    acc[t] = 0.f;
    bins[t] = 0;
    cbj[t] = cb[(size_t)t * DD + j];   // codebook column j (once per block)
    __syncthreads();
    const float* zj = z_e + (size_t)j * HW;
    float* oj = out + O_EK + (size_t)j * HW;
    const int base = c * 16384;
    float lc = 0.f;
#pragma unroll
    for (int i = 0; i < 4; ++i) {
        int n4 = base + i * 4096 + t * 4;
        int b = n4 >> 12, hw = n4 & 4095;
        size_t zoff = (size_t)b * (DD * HW) + hw;
        float4 z4 = *(const float4*)(zj + zoff);
        int4   k4 = *(const int4*)(idx_ws + n4);
        float e0 = cbj[k4.x], e1 = cbj[k4.y], e2 = cbj[k4.z], e3 = cbj[k4.w];
        float4 o4 = { z4.x + (e0 - z4.x), z4.y + (e1 - z4.y),
                      z4.z + (e2 - z4.z), z4.w + (e3 - z4.w) };
        *(float4*)(oj + zoff) = o4;                       // coalesced
        float d0 = z4.x - e0, d1 = z4.y - e1, d2 = z4.z - e2, d3 = z4.w - e3;
        lc = fmaf(d0, d0, lc); lc = fmaf(d1, d1, lc);
        lc = fmaf(d2, d2, lc); lc = fmaf(d3, d3, lc);
        atomicAdd(&acc[k4.x], z4.x);
        atomicAdd(&acc[k4.y], z4.y);
        atomicAdd(&acc[k4.z], z4.z);
        atomicAdd(&acc[k4.w], z4.w);
        if (j == 0) {
            atomicAdd(&bins[k4.x], 1); atomicAdd(&bins[k4.y], 1);
            atomicAdd(&bins[k4.z], 1); atomicAdd(&bins[k4.w], 1);
        }
    }
    __syncthreads();
    psum[(size_t)c * 65536 + j * 1024 + t] = acc[t];
    if (j == 0) pcnt[c * 1024 + t] = bins[t];
#pragma unroll
    for (int m = 32; m >= 1; m >>= 1) lc += __shfl_xor(lc, m, 64);
    if ((t & 63) == 0) lcr[t >> 6] = lc;
    __syncthreads();
    if (t == 0) {
        float s = 0.f;
#pragma unroll
        for (int u = 0; u < 16; ++u) s += lcr[u];
        lc_part[blockIdx.x] = s;
    }
}

// Fused epilogue, coalesced on outputs: e = k*64+j. 64 blocks x 1024.
__global__ __launch_bounds__(1024) void k_epi(const float* __restrict__ psum,
                                              const int* __restrict__ pcnt,
                                              const float* __restrict__ ema_sum,
                                              const float* __restrict__ ema_count,
                                              const float* __restrict__ n_ws,
                                              const float* __restrict__ lc_part,
                                              float* __restrict__ out) {
    const int t = threadIdx.x;
    const int e = blockIdx.x * 1024 + t;
    const int k = e >> 6, j = e & 63;
    float s4 = psum[j * 1024 + k] + psum[65536 + j * 1024 + k]
             + psum[131072 + j * 1024 + k] + psum[196608 + j * 1024 + k];
    float ns = ema_sum[e] * 0.99f + 0.01f * s4;
    out[O_SUM + e] = ns;
    int cnt = pcnt[k] + pcnt[1024 + k] + pcnt[2048 + k] + pcnt[3072 + k];
    float nc = ema_count[k] * 0.99f + 0.01f * (float)cnt;
    float n  = n_ws[0];
    float cs = (nc + 1e-5f) / (n + 1024.0f * 1e-5f) * n;
    out[O_CB + e] = ns / cs;
    if (blockIdx.x == 0) {
        int c2 = pcnt[t] + pcnt[1024 + t] + pcnt[2048 + t] + pcnt[3072 + t];
        out[O_CNT + t] = ema_count[t] * 0.99f + 0.01f * (float)c2;
    }
    if (blockIdx.x == 1) {
        __shared__ float red[512];
        if (t < 512) red[t] = (t < 256) ? lc_part[t] : 0.f;
        __syncthreads();
        for (int s = 256; s >= 1; s >>= 1) {
            if (t < s) red[t] += red[t + s];
            __syncthreads();
        }
        if (t == 0) out[O_L] = 1.25f * red[0] * (1.0f / 4194304.0f);
    }
}

extern "C" void kernel_launch(void* const* d_in, const int* in_sizes, int n_in,
                              void* d_out, int out_size, void* d_ws, size_t ws_size,
                              hipStream_t stream) {
    const float* z_e       = (const float*)d_in[0];
    const float* cb        = (const float*)d_in[1];
    const float* ema_count = (const float*)d_in[2];
    const float* ema_sum   = (const float*)d_in[3];
    float* out             = (float*)d_out;

    float* ws_f      = (float*)d_ws;
    int*   idx_ws    = (int*)d_ws;
    float* lc_part   = ws_f + WS_LCPART;
    float* n_ws      = ws_f + WS_N;
    float* cnorm_ws  = ws_f + WS_CNORM;
    float* psum      = ws_f + WS_PSUM;
    int*   pcnt      = (int*)(ws_f + WS_PCNT);
    int*   flg_cnt   = (int*)(ws_f + WS_FLGC);
    int*   flg_list  = (int*)(ws_f + WS_FLGL);
    unsigned short* cbh = (unsigned short*)(ws_f + WS_CBH);
    unsigned short* cbl = (unsigned short*)(ws_f + WS_CBL);

    k_pre<<<256, 256, 0, stream>>>(cb, ema_count, cnorm_ws, n_ws, cbh, cbl);
    k_argmin<<<NTOT / 128, 256, 0, stream>>>(z_e, cbh, cbl, cnorm_ws, idx_ws, flg_cnt, flg_list, out);
    k_fix<<<NTOT / 128, 256, 0, stream>>>(z_e, cb, cnorm_ws, flg_cnt, flg_list, idx_ws, out);
    k_out<<<256, 1024, 0, stream>>>(idx_ws, z_e, cb, psum, pcnt, lc_part, out);
    k_epi<<<64, 1024, 0, stream>>>(psum, pcnt, ema_sum, ema_count, n_ws, lc_part, out);
}